// Round 9
// baseline (76.403 us; speedup 1.0000x reference)
//
#include <hip/hip_runtime.h>

// Ball query via per-cell atomic slabs (no histogram, no scan, no sort).
// B=4, N1=2048 queries, N2=8192 keys, K=64, r=0.1 (cell = 0.2 = 2r).
//
// Within-cell order is IRRELEVANT because the query phase restores exact
// key order via an 8192-bit hit bitmap keyed by original index (logic
// verified R3-R8). So the "sort" is just: slab[b][cell][CAP] + global
// atomic cursor per (b,cell).
//
// Graph nodes:
//   0. hipMemsetAsync : zero the 500 cell cursors (2 KB)
//   1. build_kernel   : 128 blocks x 256 thr, one pass, zero barriers:
//                       key -> cell -> pos=atomicAdd(cursor) -> slab write.
//                       Final cursor values ARE the cell counts.
//   2. query_kernel   : 2048 blocks x 256 thr (1 query/wave, 32 waves/CU):
//                       scan <=8 octant cell slabs (L2-resident, coalesced
//                       float4 chunks), set bits in per-wave LDS bitmap,
//                       extract first K set bits in key order, pad with
//                       first-hit index.
//
// CAP=256 vs per-cell mean 65.5 (sigma ~8): overflow would need +24 sigma;
// writes are clamped so even then no memory corruption.

constexpr int   K    = 64;
constexpr float R2   = 0.01f;   // 0.1^2
constexpr int   B    = 4;
constexpr int   N1   = 2048;
constexpr int   N2   = 8192;
constexpr int   GC   = 5;                 // grid cells per dim
constexpr int   NCELL = GC * GC * GC;     // 125
constexpr float INVCELL = 5.0f;           // 1 / 0.2
constexpr int   CAP  = 256;               // slab capacity per cell

// ---------------- workspace layout ----------------
// [0, 2MB)  : slab float4 [B*NCELL*CAP]
// then      : cursors int [B*NCELL]  (zeroed by memset node; counts after build)
constexpr size_t SLAB_BYTES = (size_t)B * NCELL * CAP * 16;   // 2 MB
constexpr size_t WS_NEEDED  = SLAB_BYTES + (size_t)B * NCELL * 4;

__device__ __forceinline__ int cell_of(float v) {
    int c = (int)(v * INVCELL);
    return c < 0 ? 0 : (c > GC - 1 ? GC - 1 : c);
}

// ---------------- build: one pass, no barriers ----------------
__global__ __launch_bounds__(256) void build_kernel(
    const float* __restrict__ key,       // [B*N2, 3]
    float4* __restrict__ slab,           // [B*NCELL, CAP]
    int* __restrict__ cursors)           // [B*NCELL], pre-zeroed
{
    const int p = blockIdx.x * 256 + threadIdx.x;   // 0 .. B*N2-1
    const int b = p >> 13;
    const int i = p & (N2 - 1);
    const float x = key[p * 3 + 0];
    const float y = key[p * 3 + 1];
    const float z = key[p * 3 + 2];
    const int cell = (cell_of(x) * GC + cell_of(y)) * GC + cell_of(z);
    const int pos  = atomicAdd(&cursors[b * NCELL + cell], 1);
    if (pos < CAP) {
        float4 v;
        v.x = x; v.y = y; v.z = z; v.w = __int_as_float(i);
        slab[(size_t)(b * NCELL + cell) * CAP + pos] = v;
    }
}

// ---------------- query: 1 query per wave, 32 waves/CU ----------------
__global__ __launch_bounds__(256) void query_kernel(
    const float* __restrict__ query,     // [B*N1, 3]
    const float4* __restrict__ slab,     // [B*NCELL, CAP]
    const int* __restrict__ cursors,     // [B*NCELL] = cell counts
    int* __restrict__ out)               // [B*N1, K]
{
    __shared__ unsigned int bm[4 * 256];    // 4 waves x 8192-bit hit bitmap

    const int lane = threadIdx.x & 63;
    const int wv   = threadIdx.x >> 6;
    const int q    = blockIdx.x * 4 + wv;   // 0 .. B*N1-1
    const int b    = q >> 11;

    const float qx = query[q * 3 + 0];
    const float qy = query[q * 3 + 1];
    const float qz = query[q * 3 + 2];

    // Octant of cells the ball can touch (cell = 2r: +/-1 on near side).
    const float ux = qx * INVCELL, uy = qy * INVCELL, uz = qz * INVCELL;
    const int cx = cell_of(qx), cy = cell_of(qy), cz = cell_of(qz);
    const int nx = (ux - cx < 0.5f) ? cx - 1 : cx + 1;
    const int ny = (uy - cy < 0.5f) ? cy - 1 : cy + 1;
    const int nz = (uz - cz < 0.5f) ? cz - 1 : cz + 1;
    const int xlo = max(0, min(cx, nx)), xhi = min(GC - 1, max(cx, nx));
    const int ylo = max(0, min(cy, ny)), yhi = min(GC - 1, max(cy, ny));
    const int zlo = max(0, min(cz, nz)), zhi = min(GC - 1, max(cz, nz));

    unsigned int* wbm = bm + wv * 256;
    uint4 zz4; zz4.x = zz4.y = zz4.z = zz4.w = 0u;
    ((uint4*)wbm)[lane] = zz4;              // clear bitmap (ds_write_b128)
    __threadfence_block();

    const int*    cb = cursors + b * NCELL;
    const float4* sb = slab + (size_t)b * NCELL * CAP;

    for (int xx = xlo; xx <= xhi; ++xx) {
        for (int yy = ylo; yy <= yhi; ++yy) {
            for (int zz = zlo; zz <= zhi; ++zz) {
                const int cid = (xx * GC + yy) * GC + zz;
                const int cnt = min(cb[cid], CAP);
                const float4* run = sb + (size_t)cid * CAP;
                for (int t0 = 0; t0 < cnt; t0 += 64) {
                    const int i = t0 + lane;
                    const float4 kv = run[min(i, cnt - 1)];
                    const float dx = kv.x - qx;
                    const float dy = kv.y - qy;
                    const float dz = kv.z - qz;
                    const bool within = (i < cnt) &&
                        (dx * dx + dy * dy + dz * dz < R2);
                    if (within) {
                        const int id = __float_as_int(kv.w);
                        atomicOr(&wbm[id >> 5], 1u << (id & 31));
                    }
                }
            }
        }
    }
    __threadfence_block();

    // ---- extraction: lane owns original-index range [128*lane, 128*(lane+1))
    const uint4 w = ((const uint4*)wbm)[lane];
    const int c = __popc(w.x) + __popc(w.y) + __popc(w.z) + __popc(w.w);

    int x = c;                              // inclusive wave prefix sum
    #pragma unroll
    for (int off = 1; off < 64; off <<= 1) {
        int y = __shfl_up(x, off);
        if (lane >= off) x += y;
    }
    const int base = x - c;
    const int cnt  = __shfl(x, 63);

    int fs;                                 // first set bit (0 if none)
    if      (w.x) fs = __builtin_ctz(w.x);
    else if (w.y) fs = 32 + __builtin_ctz(w.y);
    else if (w.z) fs = 64 + __builtin_ctz(w.z);
    else if (w.w) fs = 96 + __builtin_ctz(w.w);
    else          fs = 0;
    int myfirst = c ? (lane << 7) + fs : 0x7fffffff;
    #pragma unroll
    for (int off = 32; off; off >>= 1)
        myfirst = min(myfirst, __shfl_xor(myfirst, off));
    const int firstIdx = (cnt == 0) ? 0 : myfirst;

    int* op = out + q * K;                  // emit set bits in key order
    int slot = base;
    unsigned int wr[4] = {w.x, w.y, w.z, w.w};
    #pragma unroll
    for (int r = 0; r < 4; ++r) {
        unsigned int m = wr[r];
        const int bb = (lane << 7) + (r << 5);
        while (m) {
            const int bp = __builtin_ctz(m);
            m &= m - 1;
            if (slot < K) op[slot] = bb + bp;
            ++slot;
        }
    }

    const int kpad = cnt < K ? cnt : K;     // pad with firstIdx
    const int s2 = kpad + lane;
    if (s2 < K) op[s2] = firstIdx;
}

// ---------------- fallback (ws too small): brute force ----------------
__global__ __launch_bounds__(256) void ballquery_bruteforce_kernel(
    const float* __restrict__ query, const float* __restrict__ key,
    int* __restrict__ out)
{
    const int lane = threadIdx.x & 63;
    const int q = blockIdx.x * 4 + (threadIdx.x >> 6);
    const int b = q >> 11;
    const float qx = query[q * 3], qy = query[q * 3 + 1], qz = query[q * 3 + 2];
    const float* kb = key + (size_t)b * N2 * 3;
    int* op = out + (size_t)q * K;
    int count = 0, first = 0;
    bool have_first = false;
    const unsigned long long lane_mask_lt = (lane == 0) ? 0ull : (~0ull >> (64 - lane));
    for (int c = 0; c < N2 / 64; ++c) {
        if (count >= K) break;
        const int j = (c << 6) + lane;
        const float* kp = kb + j * 3;
        const float dx = kp[0] - qx, dy = kp[1] - qy, dz = kp[2] - qz;
        const bool within = dx * dx + dy * dy + dz * dz < R2;
        const unsigned long long mask = __ballot(within);
        if (mask) {
            if (!have_first) { first = (c << 6) + __builtin_ctzll(mask); have_first = true; }
            if (within) {
                const int slot = count + __popcll(mask & lane_mask_lt);
                if (slot < K) op[slot] = j;
            }
            count += __popcll(mask);
        }
    }
    const int cnt = count < K ? count : K;
    if (cnt + lane < K) op[cnt + lane] = first;
}

extern "C" void kernel_launch(void* const* d_in, const int* in_sizes, int n_in,
                              void* d_out, int out_size, void* d_ws, size_t ws_size,
                              hipStream_t stream) {
    const float* query = (const float*)d_in[0];   // B*N1*3 floats
    const float* key   = (const float*)d_in[1];   // B*N2*3 floats
    int* out = (int*)d_out;                       // B*N1*K int32

    if (ws_size < WS_NEEDED) {
        ballquery_bruteforce_kernel<<<(B * N1) / 4, 256, 0, stream>>>(query, key, out);
        return;
    }

    float4* slab    = (float4*)d_ws;
    int*    cursors = (int*)((char*)d_ws + SLAB_BYTES);

    hipMemsetAsync(cursors, 0, (size_t)B * NCELL * 4, stream);
    build_kernel<<<(B * N2) / 256, 256, 0, stream>>>(key, slab, cursors);
    query_kernel<<<(B * N1) / 4, 256, 0, stream>>>(query, slab, cursors, out);
}